// Round 1
// 289.734 us; speedup vs baseline: 1.0033x; 1.0033x over previous
//
#include <hip/hip_runtime.h>

constexpr int DEG = 31;        // neighbors per node
constexpr int NEV = 32;        // events per node (self + neighbors)
constexpr int TH  = 16;        // threshold: dp[0..15] + absorbing "over"
constexpr int BLK = 256;
constexpr int TBL = 1 << 20;   // u8 table entries (padded >= n)

typedef int  vint4  __attribute__((ext_vector_type(4)));   // nt-compatible 16B vector

__global__ void zero_out_kernel(float* out) {
    if (threadIdx.x == 0) out[0] = 0.0f;
}

__device__ __forceinline__ float fast_sigmoid(float x) {
    return 1.0f / (1.0f + __expf(-x));
}

// ---- phase 1: u8 table tbl[i] = rint(sigmoid(gains[i])*255), packed stores ----
// Also zeroes the output scalar (folds the zero_out launch into this one).
__global__ __launch_bounds__(256)
void build_table_kernel(const float* __restrict__ gains,
                        unsigned* __restrict__ tbl4,
                        float* __restrict__ out, int n) {
    const int t = blockIdx.x * 256 + threadIdx.x;   // entries 4t..4t+3
    if (t == 0) out[0] = 0.0f;
    if (t < TBL / 4) {
        unsigned w = 0;
        #pragma unroll
        for (int k = 0; k < 4; ++k) {
            const int i = 4 * t + k;
            const float p = (i < n) ? fast_sigmoid(gains[i]) : 0.0f;
            const unsigned b = __float2uint_rn(p * 255.0f);
            w |= (b & 0xFFu) << (8 * k);
        }
        tbl4[t] = w;
    }
}

// ---- phase 2: direct gather from the L2-pinned 1 MB u8 table ----
// Streaming traffic (neighbor lists, self gains) uses nt loads so it cannot
// evict the table from L2.
// MLP discipline: ALL 31 table gathers + the p0 load are issued before any
// DP consumption (sched_barrier fence). vmcnt completion order == consumption
// order, so the waits drain as a staggered pipeline. This needs ~31 live
// gather dests + 16 dp regs; LDS caps us at 5 waves/SIMD so up to 102 VGPRs
// are free — __launch_bounds__(BLK,5) tells the allocator exactly that.
__global__ __launch_bounds__(BLK, 5)
void pgl_kernel(const float* __restrict__ gains,
                const int*   __restrict__ nbr,
                const unsigned char* __restrict__ tbl,
                float*       __restrict__ out, int n) {
    __shared__ int s_idx[BLK * DEG];          // 31744 B
    __shared__ float s_red[BLK / 64];

    const int tid        = threadIdx.x;
    const int blockStart = blockIdx.x * BLK;

    // ---- stage neighbor rows via nt 16B loads (zero-reuse stream) ----
    const int rows  = min(BLK, n - blockStart);
    const int elems = rows * DEG;
    const int base  = blockStart * DEG;
    {
        const vint4* nb4 = (const vint4*)(nbr + base);
        vint4*       s4  = (vint4*)s_idx;
        const int nvec   = elems >> 2;
        for (int v = tid; v < nvec; v += BLK)
            s4[v] = __builtin_nontemporal_load(nb4 + v);
        for (int e = (nvec << 2) + tid; e < elems; e += BLK)
            s_idx[e] = __builtin_nontemporal_load(nbr + base + e);
    }
    __syncthreads();

    float local = 0.0f;
    const int i = blockStart + tid;
    if (i < n) {
        const int* row = s_idx + tid * DEG;   // stride-31 LDS: 2-way alias (free)

        // ---- pull all 31 indices out of LDS first (kills LDS->VMEM stalls) ----
        unsigned idxs[DEG];
        #pragma unroll
        for (int j = 0; j < DEG; ++j) idxs[j] = (unsigned)row[j];

        // ---- self-gain load first: its HBM latency overlaps all 31 gathers ----
        const float g0 = __builtin_nontemporal_load(gains + i);

        // ---- 31 random u8 gathers, ALL in flight before any use ----
        unsigned gb[DEG];
        #pragma unroll
        for (int j = 0; j < DEG; ++j) gb[j] = tbl[idxs[j]];

        // fence: no load may sink below, no DP op may hoist above
        __builtin_amdgcn_sched_barrier(0);

        const float p0 = fast_sigmoid(g0);

        // ---- absorbing-state Poisson-binomial DP ----
        float dp[TH];
        dp[0] = 1.0f;
        #pragma unroll
        for (int k = 1; k < TH; ++k) dp[k] = 0.0f;
        float over = 0.0f;

        #pragma unroll
        for (int j = 0; j < NEV; ++j) {
            const float pj = (j == 0) ? p0 : (float)gb[j - 1] * (1.0f / 255.0f);
            if (j >= TH - 1) over = fmaf(dp[TH - 1], pj, over);
            const int kmax = (j + 1 < TH - 1) ? (j + 1) : (TH - 1);
            #pragma unroll
            for (int k = kmax; k >= 1; --k)
                dp[k] = fmaf(pj, dp[k - 1] - dp[k], dp[k]);
            dp[0] = fmaf(-pj, dp[0], dp[0]);
        }
        local = fmaf(0.25f, p0, -over);       // -(loss) contribution
    }

    // ---- block reduction: wave shuffle -> LDS -> one atomic per block ----
    #pragma unroll
    for (int o = 32; o > 0; o >>= 1) local += __shfl_down(local, o, 64);
    if ((tid & 63) == 0) s_red[tid >> 6] = local;
    __syncthreads();
    if (tid == 0) {
        float s = 0.0f;
        #pragma unroll
        for (int w = 0; w < BLK / 64; ++w) s += s_red[w];
        atomicAdd(out, s);
    }
}

// ---- fallback (ws too small): f32 direct gather, round-1 structure ----
__global__ __launch_bounds__(BLK)
void pgl_direct_kernel(const float* __restrict__ gains,
                       const int*   __restrict__ nbr,
                       float*       __restrict__ out, int n) {
    __shared__ int s_idx[BLK * DEG];
    __shared__ float s_red[BLK / 64];
    const int tid = threadIdx.x;
    const int blockStart = blockIdx.x * BLK;
    const int rows  = min(BLK, n - blockStart);
    const int elems = rows * DEG;
    const int base  = blockStart * DEG;
    const int4* nb4 = (const int4*)(nbr + base);
    int4* s4 = (int4*)s_idx;
    const int nvec = elems >> 2;
    for (int v = tid; v < nvec; v += BLK) s4[v] = nb4[v];
    for (int e = (nvec << 2) + tid; e < elems; e += BLK) s_idx[e] = nbr[base + e];
    __syncthreads();
    float local = 0.0f;
    const int i = blockStart + tid;
    if (i < n) {
        const int* row = s_idx + tid * DEG;
        float dp[TH];
        dp[0] = 1.0f;
        #pragma unroll
        for (int k = 1; k < TH; ++k) dp[k] = 0.0f;
        float over = 0.0f;
        const float p0 = fast_sigmoid(gains[i]);
        #pragma unroll
        for (int j = 0; j < NEV; ++j) {
            const float pj = (j == 0) ? p0 : fast_sigmoid(gains[row[j - 1]]);
            if (j >= TH - 1) over = fmaf(dp[TH - 1], pj, over);
            const int kmax = (j + 1 < TH - 1) ? (j + 1) : (TH - 1);
            #pragma unroll
            for (int k = kmax; k >= 1; --k)
                dp[k] = fmaf(pj, dp[k - 1] - dp[k], dp[k]);
            dp[0] = fmaf(-pj, dp[0], dp[0]);
        }
        local = fmaf(0.25f, p0, -over);
    }
    #pragma unroll
    for (int o = 32; o > 0; o >>= 1) local += __shfl_down(local, o, 64);
    if ((tid & 63) == 0) s_red[tid >> 6] = local;
    __syncthreads();
    if (tid == 0) {
        float s = 0.0f;
        #pragma unroll
        for (int w = 0; w < BLK / 64; ++w) s += s_red[w];
        atomicAdd(out, s);
    }
}

extern "C" void kernel_launch(void* const* d_in, const int* in_sizes, int n_in,
                              void* d_out, int out_size, void* d_ws, size_t ws_size,
                              hipStream_t stream) {
    const float* gains = (const float*)d_in[0];
    const int*   nbr   = (const int*)d_in[1];
    float*       out   = (float*)d_out;
    const int n = in_sizes[0];

    const int grid = (n + BLK - 1) / BLK;
    if (ws_size >= (size_t)TBL && n <= TBL) {
        unsigned char* tbl = (unsigned char*)d_ws;
        build_table_kernel<<<(TBL / 4 + 255) / 256, 256, 0, stream>>>(
            gains, (unsigned*)tbl, out, n);
        pgl_kernel<<<grid, BLK, 0, stream>>>(gains, nbr, tbl, out, n);
    } else {
        zero_out_kernel<<<1, 64, 0, stream>>>(out);
        pgl_direct_kernel<<<grid, BLK, 0, stream>>>(gains, nbr, out, n);
    }
}